// Round 3
// baseline (1279.979 us; speedup 1.0000x reference)
//
#include <hip/hip_runtime.h>
#include <stdint.h>
#include <stddef.h>

typedef unsigned short u16;
typedef __attribute__((ext_vector_type(8))) short short8;    // 8 bf16 input frag (4 VGPRs)
typedef __attribute__((ext_vector_type(8))) unsigned short ushort8;
typedef __attribute__((ext_vector_type(4))) float f32x4;     // MFMA 16x16 accum

#define NTOK 64
#define QKVC 1536
#define DIM  512
#define QK_REGION 4608   // per-wave u16: q[0:2048], k[2304:4352]; P[64][72] overwrites [0:4608]

__device__ __forceinline__ float bf2f(u16 u) {
  union { unsigned int i; float f; } x; x.i = ((unsigned int)u) << 16; return x.f;
}
__device__ __forceinline__ u16 f2bf(float f) {
  union { float f; unsigned int i; } x; x.f = f;
  unsigned int u = x.i;
  u += 0x7fffu + ((u >> 16) & 1u);   // RNE
  return (u16)(u >> 16);
}

// async global->LDS, 16B per lane; LDS dest = wave-uniform base + lane*16
__device__ __forceinline__ void async16(const void* g, void* l) {
  __builtin_amdgcn_global_load_lds((const __attribute__((address_space(1))) void*)g,
                                   (__attribute__((address_space(3))) void*)l,
                                   16, 0, 0);
}

__device__ __forceinline__ f32x4 shfl_xor4(f32x4 v, int m) {
  f32x4 r;
  #pragma unroll
  for (int e = 0; e < 4; ++e) r[e] = __shfl_xor(v[e], m, 64);
  return r;
}
__device__ __forceinline__ f32x4 max44(f32x4 a, f32x4 b) {
  f32x4 r;
  #pragma unroll
  for (int e = 0; e < 4; ++e) r[e] = fmaxf(a[e], b[e]);
  return r;
}

// ---------------- dtype detection ----------------
// True-bf16 w_qkv = 0.02*N(0,1): all |v| <~ 0.12 -> count 0.
// fp32-underlying read as u16 pairs: odd halves are mantissa garbage -> ~128/512 with |v|>0.5.
__global__ void detect_k(const u16* __restrict__ w_raw, int* __restrict__ flag) {
  if (threadIdx.x == 0 && blockIdx.x == 0) {
    int cnt = 0;
    for (int i = 0; i < 512; ++i) {
      float v = bf2f(w_raw[i]);
      if (!(v <= 0.5f && v >= -0.5f)) ++cnt;   // counts NaN too
    }
    flag[0] = (cnt > 16) ? 1 : 0;              // 1 = inputs are fp32
  }
}

// ---------------- prep kernels (all dtype-branching on flag) ----------------

// canonical bf16 copy: dst[i] = (bf16) src[i]
__global__ void cvt_k(const float* __restrict__ fsrc, const u16* __restrict__ usrc,
                      u16* __restrict__ dst, int n, const int* __restrict__ flag) {
  int i = blockIdx.x * 256 + threadIdx.x;
  if (i >= n) return;
  if (flag[0]) dst[i] = f2bf(fsrc[i]);
  else         dst[i] = usrc[i];
}

// dst[n*R+k] = (bf16) src[k*C+n]  (transpose to N x K)
__global__ void transpose_k(const float* __restrict__ fsrc, const u16* __restrict__ usrc,
                            u16* __restrict__ dst, int R, int C, const int* __restrict__ flag) {
  int idx = blockIdx.x * 256 + threadIdx.x;
  int n = idx / R, k = idx % R;
  if (flag[0]) dst[idx] = f2bf(fsrc[k * C + n]);
  else         dst[idx] = usrc[k * C + n];
}

// biasc[h][mi][ni][lane][r] = table[h, i1-i2+7, j1-j2+7] with
// n = mi*16 + (lane>>4)*4 + r (query row), m = ni*16 + (lane&15) (key col)
__global__ void bias_expand_k(const float* __restrict__ ftab, const u16* __restrict__ utab,
                              float* __restrict__ biasc, const int* __restrict__ flag) {
  int t = blockIdx.x * 256 + threadIdx.x;   // 65536 total
  int r    = t & 3;
  int lane = (t >> 2) & 63;
  int ni   = (t >> 8) & 3;
  int mi   = (t >> 10) & 3;
  int h    = t >> 12;
  int n = mi * 16 + (lane >> 4) * 4 + r;
  int m = ni * 16 + (lane & 15);
  int i1 = n >> 3, j1 = n & 7, i2 = m >> 3, j2 = m & 7;
  int off = h * 225 + (i1 - i2 + 7) * 15 + (j1 - j2 + 7);
  if (flag[0]) biasc[t] = ftab[off];
  else         biasc[t] = bf2f(utab[off]);
}

// ---------------- GEMM: C[M][N] = A[M][K] @ Bt[N][K]^T + bias[N] ----------------
// 128x128 tile, 4 waves (each 64x64 = 4x4 MFMA tiles), BK=32, global_load_lds staging.
// Output: bf16 to Cu, unless outf32 non-null and *outf32 -> fp32 to Cf.
__global__ __launch_bounds__(256) void gemm_bt(
    const u16* __restrict__ A, const u16* __restrict__ Bt, const u16* __restrict__ bias,
    u16* __restrict__ Cu, float* __restrict__ Cf, const int* __restrict__ outf32,
    int N, int K)
{
  __shared__ __attribute__((aligned(16))) u16 Al[128 * 32];
  __shared__ __attribute__((aligned(16))) u16 Bl[128 * 32];

  const int tn = blockIdx.x * 128;
  const int tm = blockIdx.y * 128;
  const int lane = threadIdx.x & 63;
  const int wave = threadIdx.x >> 6;
  const int lr = lane & 15, quad = lane >> 4;
  const int wm = (wave & 1) * 64, wn = (wave >> 1) * 64;

  const f32x4 zero4 = {0.f, 0.f, 0.f, 0.f};
  f32x4 acc[4][4];
  #pragma unroll
  for (int mi = 0; mi < 4; ++mi)
    #pragma unroll
    for (int ni = 0; ni < 4; ++ni) acc[mi][ni] = zero4;

  for (int k0 = 0; k0 < K; k0 += 32) {
    // stage A (128x32) and Bt (128x32); chunk c: row c>>2, elem-off (c&3)*8
    #pragma unroll
    for (int i = 0; i < 2; ++i) {
      int c = (i * 4 + wave) * 64 + lane;
      int row = c >> 2, off = (c & 3) << 3;
      async16(A  + (size_t)(tm + row) * K + k0 + off, Al + (i * 4 + wave) * 512);
      async16(Bt + (size_t)(tn + row) * K + k0 + off, Bl + (i * 4 + wave) * 512);
    }
    __syncthreads();   // drains vmcnt for the LDS-DMA

    short8 af[4], bfr[4];
    #pragma unroll
    for (int mi = 0; mi < 4; ++mi)
      af[mi] = *(const short8*)&Al[(wm + mi * 16 + lr) * 32 + quad * 8];
    #pragma unroll
    for (int ni = 0; ni < 4; ++ni)
      bfr[ni] = *(const short8*)&Bl[(wn + ni * 16 + lr) * 32 + quad * 8];

    #pragma unroll
    for (int mi = 0; mi < 4; ++mi)
      #pragma unroll
      for (int ni = 0; ni < 4; ++ni)
        acc[mi][ni] = __builtin_amdgcn_mfma_f32_16x16x32_bf16(af[mi], bfr[ni], acc[mi][ni], 0, 0, 0);
    __syncthreads();
  }

  // epilogue: C-layout col = lane&15, row = quad*4 + r
  const int f32o = outf32 ? outf32[0] : 0;
  #pragma unroll
  for (int ni = 0; ni < 4; ++ni) {
    int col = tn + wn + ni * 16 + lr;
    float bv = bf2f(bias[col]);
    #pragma unroll
    for (int mi = 0; mi < 4; ++mi) {
      size_t rb = (size_t)(tm + wm + mi * 16 + quad * 4);
      #pragma unroll
      for (int r = 0; r < 4; ++r) {
        float val = acc[mi][ni][r] + bv;
        size_t ofs = (rb + r) * (size_t)N + col;
        if (f32o) Cf[ofs] = val;
        else      Cu[ofs] = f2bf(val);
      }
    }
  }
}

// ---------------- fused window attention: one wave per (window,head) ----------------
__global__ __launch_bounds__(256) void attn_k(
    const u16* __restrict__ qkv,      // [win*64][1536] chunk
    const float* __restrict__ biasc,  // [16][4][4][64][4] C-layout expanded bias
    u16* __restrict__ out)            // [win*64][512] chunk
{
  __shared__ __attribute__((aligned(16))) u16 qkP[4][QK_REGION];
  __shared__ __attribute__((aligned(16))) u16 vTs[4][32 * 72];  // per wave: v^T [d][token], stride 72

  const int lane = threadIdx.x & 63;
  const int wave = threadIdx.x >> 6;
  const int idx = blockIdx.x * 4 + wave;   // (b,h) within chunk
  const int b = idx >> 4, h = idx & 15;
  const int lr = lane & 15, quad = lane >> 4;

  u16* ql = qkP[wave];
  u16* kl = qkP[wave] + 2304;
  u16* Pl = qkP[wave];                     // P[64][72], overwrites dead q/k
  u16* vt = vTs[wave];

  const u16* qg = qkv + (size_t)b * NTOK * QKVC + h * 32;
  const u16* kg = qg + 512;
  const u16* vg = qg + 1024;

  // stage q,k (64x32 bf16 each) via LDS-DMA
  #pragma unroll
  for (int i = 0; i < 4; ++i) {
    int c = i * 64 + lane;
    int row = c >> 2, off = (c & 3) << 3;
    async16(qg + (size_t)row * QKVC + off, ql + i * 512);
    async16(kg + (size_t)row * QKVC + off, kl + i * 512);
  }
  // stage v transposed via VGPRs: vt[d*72 + token]
  {
    const u16* vrow = vg + (size_t)lane * QKVC;   // token = lane
    #pragma unroll
    for (int c2 = 0; c2 < 4; ++c2) {
      ushort8 vv = *(const ushort8*)(vrow + c2 * 8);
      #pragma unroll
      for (int e = 0; e < 8; ++e)
        vt[(c2 * 8 + e) * 72 + lane] = vv[e];
    }
  }
  __syncthreads();   // full fence: drains LDS-DMA vmcnt + ds_writes, blocks reordering

  // S = q @ k^T : 4x4 tiles of 16x16, K=32 (one MFMA step)
  const f32x4 zero4 = {0.f, 0.f, 0.f, 0.f};
  f32x4 s[4][4];
  {
    short8 af[4], bfr[4];
    #pragma unroll
    for (int mi = 0; mi < 4; ++mi)
      af[mi] = *(const short8*)&ql[(mi * 16 + lr) * 32 + quad * 8];
    #pragma unroll
    for (int ni = 0; ni < 4; ++ni)
      bfr[ni] = *(const short8*)&kl[(ni * 16 + lr) * 32 + quad * 8];
    #pragma unroll
    for (int mi = 0; mi < 4; ++mi)
      #pragma unroll
      for (int ni = 0; ni < 4; ++ni)
        s[mi][ni] = __builtin_amdgcn_mfma_f32_16x16x32_bf16(af[mi], bfr[ni], zero4, 0, 0, 0);
  }

  // scale + rel-pos bias (pre-expanded in C-layout, coalesced float4 loads)
  const float SCALE = 0.17677669529663687f;   // 32^-0.5
  const float L2E = 1.44269504088896f;
  #pragma unroll
  for (int mi = 0; mi < 4; ++mi)
    #pragma unroll
    for (int ni = 0; ni < 4; ++ni) {
      f32x4 bb = *(const f32x4*)&biasc[((((h * 4 + mi) * 4 + ni) * 64) + lane) * 4];
      s[mi][ni] = s[mi][ni] * SCALE + bb;
    }

  // row max (masks 1..8 stay within the quad's 16-lane col group)
  f32x4 mx[4];
  #pragma unroll
  for (int mi = 0; mi < 4; ++mi) {
    mx[mi] = max44(max44(s[mi][0], s[mi][1]), max44(s[mi][2], s[mi][3]));
    #pragma unroll
    for (int m = 1; m <= 8; m <<= 1) mx[mi] = max44(mx[mi], shfl_xor4(mx[mi], m));
  }
  // p = exp(s - mx), row sum
  f32x4 sum[4];
  #pragma unroll
  for (int mi = 0; mi < 4; ++mi) {
    #pragma unroll
    for (int ni = 0; ni < 4; ++ni)
      #pragma unroll
      for (int e = 0; e < 4; ++e)
        s[mi][ni][e] = exp2f((s[mi][ni][e] - mx[mi][e]) * L2E);
    sum[mi] = s[mi][0] + s[mi][1] + s[mi][2] + s[mi][3];
    #pragma unroll
    for (int m = 1; m <= 8; m <<= 1) sum[mi] = sum[mi] + shfl_xor4(sum[mi], m);
  }

  // P (unnormalized) -> bf16 -> LDS, padded stride 72 (2-way bank aliasing = free)
  #pragma unroll
  for (int mi = 0; mi < 4; ++mi)
    #pragma unroll
    for (int ni = 0; ni < 4; ++ni)
      #pragma unroll
      for (int r = 0; r < 4; ++r) {
        int n = mi * 16 + quad * 4 + r;
        int col = ni * 16 + lr;
        Pl[n * 72 + col] = f2bf(s[mi][ni][r]);
      }
  __syncthreads();   // fence P stores before re-reading the region

  // O = P @ v : M=64, N=32, K=64 (2 k-steps)
  f32x4 o[4][2];
  #pragma unroll
  for (int mi = 0; mi < 4; ++mi) { o[mi][0] = zero4; o[mi][1] = zero4; }
  #pragma unroll
  for (int ks = 0; ks < 2; ++ks) {
    short8 pf[4], vf[2];
    #pragma unroll
    for (int mi = 0; mi < 4; ++mi)
      pf[mi] = *(const short8*)&Pl[(mi * 16 + lr) * 72 + ks * 32 + quad * 8];
    #pragma unroll
    for (int ni = 0; ni < 2; ++ni)
      vf[ni] = *(const short8*)&vt[(ni * 16 + lr) * 72 + ks * 32 + quad * 8];
    #pragma unroll
    for (int mi = 0; mi < 4; ++mi)
      #pragma unroll
      for (int ni = 0; ni < 2; ++ni)
        o[mi][ni] = __builtin_amdgcn_mfma_f32_16x16x32_bf16(pf[mi], vf[ni], o[mi][ni], 0, 0, 0);
  }

  // normalize by row sum, write out[b*64+n][h*32+d]
  f32x4 rs[4];
  #pragma unroll
  for (int mi = 0; mi < 4; ++mi)
    #pragma unroll
    for (int e = 0; e < 4; ++e) rs[mi][e] = __builtin_amdgcn_rcpf(sum[mi][e]);

  #pragma unroll
  for (int mi = 0; mi < 4; ++mi)
    #pragma unroll
    for (int ni = 0; ni < 2; ++ni)
      #pragma unroll
      for (int r = 0; r < 4; ++r) {
        int n = mi * 16 + quad * 4 + r;
        int d = ni * 16 + lr;
        out[(size_t)(b * NTOK + n) * DIM + h * 32 + d] = f2bf(o[mi][ni][r] * rs[mi][r]);
      }
}

// ---------------- launch ----------------

extern "C" void kernel_launch(void* const* d_in, const int* in_sizes, int n_in,
                              void* d_out, int out_size, void* d_ws, size_t ws_size,
                              hipStream_t stream)
{
  (void)in_sizes; (void)n_in; (void)out_size;

  const void* x      = d_in[0];   // [2048*64][512]
  const void* w_qkv  = d_in[1];   // [512][1536]
  const void* b_qkv  = d_in[2];   // [1536]
  const void* table  = d_in[3];   // [16][15][15]
  const void* w_proj = d_in[4];   // [512][512]
  const void* b_proj = d_in[5];   // [512]

  // workspace layout, sized against ws_size at runtime
  char* ws = (char*)d_ws;
  size_t off = 0;
  auto alloc = [&](size_t bytes) -> char* {
    char* p = ws + off; off += (bytes + 255) & ~(size_t)255; return p;
  };
  u16*   wqkvT  = (u16*)alloc(1572864);
  u16*   wprojT = (u16*)alloc(524288);
  float* biasc  = (float*)alloc(262144);
  u16*   bqc    = (u16*)alloc(3072);
  u16*   bpc    = (u16*)alloc(1024);
  int*   flag   = (int*)alloc(256);
  size_t fixed  = off;

  int win = 256;                         // windows per chunk
  while (win > 2 && fixed + (size_t)win * 327680 > ws_size) win >>= 1;
  const int mc = win * 64;               // rows per chunk
  u16* xbfC  = (u16*)alloc((size_t)mc * 512 * 2);
  u16* qkvC  = (u16*)alloc((size_t)mc * 1536 * 2);
  u16* aoutC = (u16*)alloc((size_t)mc * 512 * 2);

  detect_k<<<dim3(1), dim3(64), 0, stream>>>((const u16*)w_qkv, flag);
  transpose_k<<<dim3(3072), dim3(256), 0, stream>>>((const float*)w_qkv, (const u16*)w_qkv, wqkvT, 512, 1536, flag);
  transpose_k<<<dim3(1024), dim3(256), 0, stream>>>((const float*)w_proj, (const u16*)w_proj, wprojT, 512, 512, flag);
  bias_expand_k<<<dim3(256), dim3(256), 0, stream>>>((const float*)table, (const u16*)table, biasc, flag);
  cvt_k<<<dim3(6), dim3(256), 0, stream>>>((const float*)b_qkv, (const u16*)b_qkv, bqc, 1536, flag);
  cvt_k<<<dim3(2), dim3(256), 0, stream>>>((const float*)b_proj, (const u16*)b_proj, bpc, 512, flag);

  const int nchunk = 2048 / win;
  for (int c = 0; c < nchunk; ++c) {
    size_t base = (size_t)c * mc * 512;   // element offset into x / out

    // canonical-bf16 x chunk
    cvt_k<<<dim3((mc * 512) / 256), dim3(256), 0, stream>>>(
        (const float*)x + base, (const u16*)x + base, xbfC, mc * 512, flag);

    // qkv = x @ w_qkv + b_qkv   (M=mc, N=1536, K=512), bf16 out
    gemm_bt<<<dim3(12, mc / 128), dim3(256), 0, stream>>>(
        xbfC, wqkvT, bqc, qkvC, (float*)nullptr, (const int*)nullptr, 1536, 512);

    // per-window attention
    attn_k<<<dim3(win * 4), dim3(256), 0, stream>>>(qkvC, biasc, aoutC);

    // out = aout @ w_proj + b_proj   (M=mc, N=512, K=512), dtype per flag
    gemm_bt<<<dim3(4, mc / 128), dim3(256), 0, stream>>>(
        aoutC, wprojT, bpc, (u16*)d_out + base, (float*)d_out + base, flag, 512, 512);
  }
}